// Round 1
// 628.108 us; speedup vs baseline: 1.0801x; 1.0801x over previous
//
#include <hip/hip_runtime.h>
#include <stdint.h>

// Masker: reproduce JAX threefry RNG (partitionable/fold-like semantics,
// default since jax 0.4.30) to build the per-batch mask, then apply it.
//
// d_out layout: [masked patches: 32*4096*768 f32][mask: 32*4096 f32 (0/1)]
//
// v2: replace the barrier-bound in-LDS bitonic sort (156 __syncthreads,
// LDS-latency critical path) with exact rank computation via bucketed
// counting: histogram top-10 key bits into 1024 buckets (~4 elems each),
// shfl-based prefix scan, scatter, then rank = bucket_base + #smaller
// within bucket. Bit-identical keys => identical permutation.
// Also: apply kernel skips the input load for masked rows (-12% fetch).

namespace {

constexpr int kB = 32;
constexpr int kN = 4096;
constexpr int kD = 768;
constexpr int kTake = 614;  // int(4096 * 0.15)
constexpr size_t kMaskOff = (size_t)kB * kN * kD;
constexpr int kBkt = 1024;  // buckets on top-10 bits of the 32-bit sort key

__device__ __forceinline__ uint32_t rotl32(uint32_t v, int d) {
  return (v << d) | (v >> (32 - d));
}

// JAX threefry-2x32, 20 rounds (jax/_src/prng.py reference impl).
__device__ __forceinline__ void tf2x32(uint32_t k0, uint32_t k1,
                                       uint32_t x0, uint32_t x1,
                                       uint32_t &o0, uint32_t &o1) {
  const uint32_t k2 = k0 ^ k1 ^ 0x1BD11BDAu;
  x0 += k0; x1 += k1;
#define TF_R(r) { x0 += x1; x1 = rotl32(x1, (r)); x1 ^= x0; }
  TF_R(13) TF_R(15) TF_R(26) TF_R(6)   x0 += k1; x1 += k2 + 1u;
  TF_R(17) TF_R(29) TF_R(16) TF_R(24)  x0 += k2; x1 += k0 + 2u;
  TF_R(13) TF_R(15) TF_R(26) TF_R(6)   x0 += k0; x1 += k1 + 3u;
  TF_R(17) TF_R(29) TF_R(16) TF_R(24)  x0 += k1; x1 += k2 + 4u;
  TF_R(13) TF_R(15) TF_R(26) TF_R(6)   x0 += k2; x1 += k0 + 5u;
#undef TF_R
  o0 = x0; o1 = x1;
}

// Partitionable random_bits(key, 32, (n,)): element i = xor of the two
// output words of the threefry block with counter (hi=0, lo=i).
__device__ __forceinline__ uint32_t tf_bits(uint32_t k0, uint32_t k1,
                                            uint32_t i) {
  uint32_t a, b;
  tf2x32(k0, k1, 0u, i, a, b);
  return a ^ b;
}

}  // namespace

extern "C" __global__ __launch_bounds__(1024) void masker_mask_kernel(
    float *__restrict__ maskf) {
  __shared__ uint64_t karr[kN];                 // 32 KB bucketed composite keys
  __shared__ uint32_t scnt[kBkt];               // 4 KB histogram / cursors
  __shared__ uint32_t scur[kBkt];               // 4 KB scatter cursors
  __shared__ uint32_t sbase[kBkt + 1];          // 4 KB exclusive bucket bases
  __shared__ uint16_t sx1[kN];                  // 8 KB round-1 sorted array
  __shared__ uint32_t swsum[16];                // per-wave scan sums
  __shared__ unsigned long long smaskbits[kN / 64];  // 512 B packed mask

  const int b = blockIdx.x;
  const int tid = threadIdx.x;
  const int lane = tid & 63;
  const int wid = tid >> 6;

  // Key chain (all fold-like splits: subkey i = TF(key, (0, i))):
  uint32_t kb0, kb1, kp0, kp1, kr0, kr1, k10, k11, s10, s11, s20, s21;
  tf2x32(0u, 42u, 0u, (uint32_t)b, kb0, kb1);  // keys[b] of split(key(42),32)
  tf2x32(kb0, kb1, 0u, 0u, kp0, kp1);          // k_perm
  tf2x32(kb0, kb1, 0u, 1u, kr0, kr1);          // k_bern
  tf2x32(kp0, kp1, 0u, 0u, k10, k11);          // shuffle round1: carried key
  tf2x32(kp0, kp1, 0u, 1u, s10, s11);          // shuffle round1: subkey
  tf2x32(k10, k11, 0u, 1u, s20, s21);          // shuffle round2: subkey

  // Inclusive scan over scnt[kBkt] -> exclusive bases in sbase[0..kBkt].
  // kBkt == blockDim == 1024, 3 barriers total (shfl wave scans).
  auto scan_bases = [&]() {
    uint32_t x = scnt[tid];
#pragma unroll
    for (int d = 1; d < 64; d <<= 1) {
      uint32_t y = __shfl_up(x, d, 64);
      if (lane >= d) x += y;
    }
    if (lane == 63) swsum[wid] = x;
    __syncthreads();
    if (wid == 0) {
      uint32_t w = (lane < 16) ? swsum[lane] : 0u;
#pragma unroll
      for (int d = 1; d < 16; d <<= 1) {
        uint32_t y = __shfl_up(w, d, 64);
        if (lane >= d) w += y;
      }
      if (lane < 16) swsum[lane] = w;  // inclusive wave sums
    }
    __syncthreads();
    const uint32_t off = (wid > 0) ? swsum[wid - 1] : 0u;
    sbase[tid + 1] = x + off;
    if (tid == 0) sbase[0] = 0u;
    __syncthreads();
  };

  // ---------------- Round 1: stable sort arange(4096) by bits1 -------------
  // Composite key (bits<<12 | j) is unique; rank(j) = #{key' < key(j)}.
  scnt[tid] = 0u;
  scur[tid] = 0u;
  __syncthreads();

  uint32_t mybits[4];
#pragma unroll
  for (int e = 0; e < 4; ++e) {
    const int j = tid + e * 1024;
    const uint32_t bits = tf_bits(s10, s11, (uint32_t)j);
    mybits[e] = bits;
    atomicAdd(&scnt[bits >> 22], 1u);
  }
  __syncthreads();
  scan_bases();

#pragma unroll
  for (int e = 0; e < 4; ++e) {
    const int j = tid + e * 1024;
    const uint32_t bits = mybits[e];
    const uint32_t slot = sbase[bits >> 22] + atomicAdd(&scur[bits >> 22], 1u);
    karr[slot] = ((uint64_t)bits << 12) | (uint32_t)j;
  }
  __syncthreads();

#pragma unroll
  for (int e = 0; e < 4; ++e) {
    const int j = tid + e * 1024;
    const uint64_t myk = ((uint64_t)mybits[e] << 12) | (uint32_t)j;
    const uint32_t bkt = mybits[e] >> 22;
    uint32_t r = sbase[bkt];
    const uint32_t end = sbase[bkt + 1];
    for (uint32_t t = sbase[bkt]; t < end; ++t) r += (karr[t] < myk) ? 1u : 0u;
    sx1[r] = (uint16_t)j;  // ranks unique -> no conflicts
  }
  __syncthreads();

  // ---------------- Round 2: stable sort x1 by bits2 -----------------------
  // Key (bits2(p)<<12 | p): same ordering as (bits2, p, x1[p]) since p unique.
  scnt[tid] = 0u;
  scur[tid] = 0u;
  if (tid < kN / 64) smaskbits[tid] = 0ull;
  __syncthreads();

#pragma unroll
  for (int e = 0; e < 4; ++e) {
    const int p = tid + e * 1024;
    const uint32_t bits = tf_bits(s20, s21, (uint32_t)p);
    mybits[e] = bits;
    atomicAdd(&scnt[bits >> 22], 1u);
  }
  __syncthreads();
  scan_bases();

#pragma unroll
  for (int e = 0; e < 4; ++e) {
    const int p = tid + e * 1024;
    const uint32_t bits = mybits[e];
    const uint32_t slot = sbase[bits >> 22] + atomicAdd(&scur[bits >> 22], 1u);
    karr[slot] = ((uint64_t)bits << 12) | (uint32_t)p;
  }
  __syncthreads();

#pragma unroll
  for (int e = 0; e < 4; ++e) {
    const int p = tid + e * 1024;
    const uint64_t myk = ((uint64_t)mybits[e] << 12) | (uint32_t)p;
    const uint32_t bkt = mybits[e] >> 22;
    uint32_t r = sbase[bkt];
    const uint32_t end = sbase[bkt + 1];
    for (uint32_t t = sbase[bkt]; t < end; ++t) r += (karr[t] < myk) ? 1u : 0u;
    // perm[r] = x1[p]; idx = perm[:614], bern draw indexed by position r.
    if (r < (uint32_t)kTake) {
      const uint32_t v = sx1[p];
      const uint32_t ub = tf_bits(kr0, kr1, r);
      const float u = __uint_as_float((ub >> 9) | 0x3f800000u) - 1.0f;
      if (u < 0.8f && v != 0u)
        atomicOr(&smaskbits[v >> 6], 1ull << (v & 63));
    }
  }
  __syncthreads();

  float *row = maskf + (size_t)b * kN;
#pragma unroll
  for (int e = 0; e < 4; ++e) {
    const int n = tid + e * 1024;
    row[n] = ((smaskbits[n >> 6] >> (n & 63)) & 1ull) ? 1.0f : 0.0f;
  }
}

extern "C" __global__ __launch_bounds__(256) void masker_apply_kernel(
    const float4 *__restrict__ in, float4 *__restrict__ out,
    const float *__restrict__ maskf) {
  const int gid = blockIdx.x * 256 + threadIdx.x;
  const int row = gid / (kD / 4);  // 192 float4 per (b, n) row
  const float m = maskf[row];
  float4 v = make_float4(0.f, 0.f, 0.f, 0.f);
  // Skip the input fetch entirely for masked rows (~12% of fetch traffic);
  // rows are 3072 B and cacheline-aligned, so skipped lines never leave HBM.
  if (m == 0.0f) v = in[gid];
  out[gid] = v;
}

extern "C" void kernel_launch(void* const* d_in, const int* in_sizes, int n_in,
                              void* d_out, int out_size, void* d_ws,
                              size_t ws_size, hipStream_t stream) {
  (void)in_sizes; (void)n_in; (void)out_size; (void)d_ws; (void)ws_size;
  const float* in = (const float*)d_in[0];
  float* out = (float*)d_out;
  float* maskf = out + kMaskOff;

  masker_mask_kernel<<<kB, 1024, 0, stream>>>(maskf);

  const int n4 = (kB * kN * kD) / 4;          // 25,165,824 float4
  masker_apply_kernel<<<n4 / 256, 256, 0, stream>>>(
      (const float4*)in, (float4*)out, maskf);
}